// Round 2
// baseline (375.926 us; speedup 1.0000x reference)
//
#include <hip/hip_runtime.h>
#include <math.h>

#define N_NODES 50000
#define N_EDGES 800000
#define D_IN 128
#define D1 150
#define LD1 152   // h1 leading dim (16B-aligned rows; pad cols written 0)
#define D2 100
#define LDP 128   // p / ns leading dim (alignment; pad cols written 0, never read)
#define D_OUT 64
#define SLOT 64   // fixed bucket capacity per dst node; P(deg_in>64) ~ 1e-15 (Poisson 16)
#define HBLK 64   // histogram shards (deg_out via LDS atomics)
#define HBIN 12500  // 50000 bins packed 4 x u8 per int

#define LDS_K 40  // LDS k-stride (32 used + 8 pad) -> 80B rows, b128-conflict-free

using short8 = __attribute__((ext_vector_type(8))) short;   // 8 bf16 (4 VGPRs)
using f32x4  = __attribute__((ext_vector_type(4))) float;   // MFMA accumulator

__device__ __forceinline__ float elu(float v) { return v > 0.0f ? v : expm1f(v); }

// fp32 -> bf16 hi/lo split (round-to-nearest via +0x8000 trick).
__device__ __forceinline__ void split_bf16(float a, unsigned short& h, unsigned short& l) {
    unsigned int bits = __float_as_uint(a);
    unsigned int hb = (bits + 0x8000u) >> 16;
    h = (unsigned short)hb;
    float r = a - __uint_as_float(hb << 16);
    l = (unsigned short)((__float_as_uint(r) + 0x8000u) >> 16);
}

// split 16 fp32 -> two short8 hi + two short8 lo and store to LDS row (b128 x4)
__device__ __forceinline__ void split_store16(unsigned short* hrow, unsigned short* lrow,
                                              const float* vv) {
    short8 h0, h1v, l0, l1v;
#pragma unroll
    for (int i = 0; i < 8; ++i) {
        unsigned short hh, ll;
        split_bf16(vv[i], hh, ll);
        h0[i] = (short)hh; l0[i] = (short)ll;
    }
#pragma unroll
    for (int i = 0; i < 8; ++i) {
        unsigned short hh, ll;
        split_bf16(vv[8 + i], hh, ll);
        h1v[i] = (short)hh; l1v[i] = (short)ll;
    }
    *(short8*)(hrow) = h0;
    *(short8*)(hrow + 8) = h1v;
    *(short8*)(lrow) = l0;
    *(short8*)(lrow + 8) = l1v;
}

// ---------------- deg_out histogram via LDS atomics ----------------
__global__ __launch_bounds__(256) void hist_kernel(const int* __restrict__ src,
                                                   unsigned int* __restrict__ partial) {
    __shared__ unsigned int bins[HBIN];   // 50 KB
    int tid = threadIdx.x, b = blockIdx.x;
    for (int i = tid; i < HBIN; i += 256) bins[i] = 0u;
    __syncthreads();
    int e0 = b * (N_EDGES / HBLK);
    int e1 = e0 + (N_EDGES / HBLK);
    for (int e = e0 + tid; e < e1; e += 256) {
        int s = src[e];
        atomicAdd(&bins[s >> 2], 1u << ((s & 3) * 8));
    }
    __syncthreads();
    unsigned int* outp = partial + (size_t)b * HBIN;
    for (int i = tid; i < HBIN; i += 256) outp[i] = bins[i];
}

// ---------------- norm_out[n] = rsqrt(max(deg_out,1)) from packed partials ----------------
__global__ __launch_bounds__(256) void norm_kernel(const unsigned int* __restrict__ partial,
                                                   float* __restrict__ norm_out) {
    int i = blockIdx.x * blockDim.x + threadIdx.x;   // int position: 4 nodes
    if (i >= HBIN) return;
    unsigned int acc = 0;
#pragma unroll
    for (int h = 0; h < HBLK; ++h) acc += partial[(size_t)h * HBIN + i];
#pragma unroll
    for (int j = 0; j < 4; ++j) {
        unsigned int dg = (acc >> (j * 8)) & 0xFF;
        norm_out[i * 4 + j] = rsqrtf(fmaxf((float)dg, 1.0f));
    }
}

// ---------------- bucket fill: cursor atomic + slot store only (800k atomics) ----------------
__global__ void fill_kernel(const int* __restrict__ src, const int* __restrict__ dst,
                            int* __restrict__ cursor, unsigned short* __restrict__ slots) {
    int e = blockIdx.x * blockDim.x + threadIdx.x;
    if (e < N_EDGES) {
        int d = dst[e], s = src[e];
        int pos = atomicAdd(&cursor[d], 1);
        if (pos < SLOT) slots[d * SLOT + pos] = (unsigned short)s;
    }
}

// ---------------- gather 1: agg[n] = sum_e x[src[e]] * norm_out[src[e]] ----------------
__global__ __launch_bounds__(256) void gather_x(const float* __restrict__ x,
                                                const float* __restrict__ norm_out,
                                                const int* __restrict__ deg_in,
                                                const unsigned short* __restrict__ slots,
                                                float* __restrict__ agg) {
    int wave = threadIdx.x >> 6;
    int lane = threadIdx.x & 63;
    int half = lane >> 5;
    int c = lane & 31;
    int n = blockIdx.x * 4 + wave;
    if (n >= N_NODES) return;
    int beg = n * SLOT;
    int dg = deg_in[n]; if (dg > SLOT) dg = SLOT;
    int end = beg + dg;
    float4 acc = {0.0f, 0.0f, 0.0f, 0.0f};
    int e = beg + half;
    for (; e + 2 < end; e += 4) {
        int s0 = slots[e];
        int s1 = slots[e + 2];
        float w0 = norm_out[s0], w1 = norm_out[s1];
        float4 v0 = ((const float4*)(x + (size_t)s0 * D_IN))[c];
        float4 v1 = ((const float4*)(x + (size_t)s1 * D_IN))[c];
        acc.x += v0.x * w0 + v1.x * w1;
        acc.y += v0.y * w0 + v1.y * w1;
        acc.z += v0.z * w0 + v1.z * w1;
        acc.w += v0.w * w0 + v1.w * w1;
    }
    if (e < end) {
        int s = slots[e];
        float w = norm_out[s];
        float4 v = ((const float4*)(x + (size_t)s * D_IN))[c];
        acc.x += v.x * w; acc.y += v.y * w; acc.z += v.z * w; acc.w += v.w * w;
    }
    acc.x += __shfl_xor(acc.x, 32);
    acc.y += __shfl_xor(acc.y, 32);
    acc.z += __shfl_xor(acc.z, 32);
    acc.w += __shfl_xor(acc.w, 32);
    if (half == 0) ((float4*)(agg + (size_t)n * D_IN))[c] = acc;
}

// ---------------- gather 2: ns[n] = sum_e p[src[e]]  (only cols 0..99 read) ----------------
__global__ __launch_bounds__(256) void gather_p(const float* __restrict__ p,
                                                const int* __restrict__ deg_in,
                                                const unsigned short* __restrict__ slots,
                                                float* __restrict__ ns) {
    int wave = threadIdx.x >> 6;
    int lane = threadIdx.x & 63;
    int half = lane >> 5;
    int c = lane & 31;
    bool cv = c < D2 / 4;
    int n = blockIdx.x * 4 + wave;
    if (n >= N_NODES) return;
    int beg = n * SLOT;
    int dg = deg_in[n]; if (dg > SLOT) dg = SLOT;
    int end = beg + dg;
    float4 acc = {0.0f, 0.0f, 0.0f, 0.0f};
    if (cv) {
        int e = beg + half;
        for (; e + 2 < end; e += 4) {
            int s0 = slots[e];
            int s1 = slots[e + 2];
            float4 v0 = ((const float4*)(p + (size_t)s0 * LDP))[c];
            float4 v1 = ((const float4*)(p + (size_t)s1 * LDP))[c];
            acc.x += v0.x + v1.x;
            acc.y += v0.y + v1.y;
            acc.z += v0.z + v1.z;
            acc.w += v0.w + v1.w;
        }
        if (e < end) {
            int s = slots[e];
            float4 v = ((const float4*)(p + (size_t)s * LDP))[c];
            acc.x += v.x; acc.y += v.y; acc.z += v.z; acc.w += v.w;
        }
    }
    acc.x += __shfl_xor(acc.x, 32);
    acc.y += __shfl_xor(acc.y, 32);
    acc.z += __shfl_xor(acc.z, 32);
    acc.w += __shfl_xor(acc.w, 32);
    if (half == 0 && cv) ((float4*)(ns + (size_t)n * LDP))[c] = acc;
}

// ======================= split-bf16 MFMA GEMM, prefetch-pipelined =======================
// BM=128, BN=64, BK=32. 4 waves 2Mx2N; wave tile 64x32 = 4x2 frags; 3 MFMAs/frag (hh,lh,hl).
// Pipeline: iter t issues tile t+1's global loads into ping-pong regs BEFORE the barriers,
// so they fly under barrier+stage+barrier+ds_read+MFMA (~1500cyc cover). Single LDS buffer,
// 2 barriers/step, fully unrolled K-loop (NSTEP<=5) so buffer indices are compile-time.
// Grid swizzle: the GROUP n-tile siblings sharing an A row-panel map to CONSECUTIVE slots
// on the SAME XCD (b%8 round-robin), so the panel is fetched once into that XCD's L2.
// C/D layout (verified): col = lane&15, row = (lane>>4)*4 + reg.

template <int K, int KP, int NW, int LDA, int PRE, int EPI, int LDC, int GROUP>
__global__ __launch_bounds__(256, PRE ? 2 : 3)
void gemm_mfma(const float* __restrict__ A, const float* __restrict__ W,
               const float* __restrict__ nsrc, const int* __restrict__ deg,
               const float* __restrict__ bstage, const float* __restrict__ bepi,
               float* __restrict__ C) {
    constexpr int NSTEP = KP / 32;
    constexpr int MBLK = (N_NODES + 127) / 128;
    __shared__ __align__(16) unsigned short AsH[128][LDS_K];
    __shared__ __align__(16) unsigned short AsL[128][LDS_K];
    __shared__ __align__(16) unsigned short BsH[64][LDS_K];
    __shared__ __align__(16) unsigned short BsL[64][LDS_K];

    // XCD-sibling swizzle: c = xcd, s = slot on that xcd; GROUP consecutive slots share x.
    const int b = blockIdx.x;
    const int c = b & 7;
    const int sIdx = b >> 3;
    const int jj = sIdx / GROUP;
    const int yy = sIdx - jj * GROUP;
    const int xb = c + 8 * jj;
    if (xb >= MBLK) return;
    const int m0 = xb * 128;
    const int n0 = yy * 64;

    const int tid = threadIdx.x;
    const int arow = tid >> 1;
    const int af = (tid & 1) * 16;
    const int grow = m0 + arow;
    const int bn = tid & 63;
    const int bkg = tid >> 6;
    const int bcol = n0 + bn;
    const int wid = tid >> 6;
    const int lane = tid & 63;
    const int wm = (wid >> 1) * 64;
    const int wn = (wid & 1) * 32;
    const int fr = lane & 15;
    const int fg = lane >> 4;

    float invd = 1.0f;
    if (PRE) {
        int dv = (grow < N_NODES) ? deg[grow] : 1;
        invd = 1.0f / fmaxf((float)dv, 1.0f);
    }

    f32x4 acc[4][2];
#pragma unroll
    for (int i = 0; i < 4; ++i)
#pragma unroll
        for (int j = 0; j < 2; ++j) acc[i][j] = {0.0f, 0.0f, 0.0f, 0.0f};

    auto load_a = [&](int k0, float* vA, float* vN) {
        if (grow < N_NODES && k0 + 32 <= K) {
            const float* ap = A + (size_t)grow * LDA + k0 + af;
#pragma unroll
            for (int h = 0; h < 4; ++h) {
                float4 v = *(const float4*)(ap + h * 4);
                vA[h * 4 + 0] = v.x; vA[h * 4 + 1] = v.y;
                vA[h * 4 + 2] = v.z; vA[h * 4 + 3] = v.w;
            }
            if (PRE) {
                const float* np = nsrc + (size_t)grow * LDP + k0 + af;
#pragma unroll
                for (int h = 0; h < 4; ++h) {
                    float4 v = *(const float4*)(np + h * 4);
                    vN[h * 4 + 0] = v.x; vN[h * 4 + 1] = v.y;
                    vN[h * 4 + 2] = v.z; vN[h * 4 + 3] = v.w;
                }
            }
        } else {
#pragma unroll
            for (int i = 0; i < 16; ++i) {
                int k = k0 + af + i;
                bool ok = (grow < N_NODES && k < K);
                vA[i] = ok ? A[(size_t)grow * LDA + k] : 0.0f;
                if (PRE) vN[i] = ok ? nsrc[(size_t)grow * LDP + k] : 0.0f;
            }
        }
    };
    auto load_b = [&](int k0, float* vB) {
#pragma unroll
        for (int kk = 0; kk < 8; ++kk) {
            int k = k0 + bkg * 8 + kk;
            vB[kk] = (k < K && bcol < NW) ? W[(size_t)k * NW + bcol] : 0.0f;
        }
    };
    auto stage = [&](int k0, const float* vA, const float* vN, const float* vB) {
        float tv[16];
        if (!PRE) {
#pragma unroll
            for (int i = 0; i < 16; ++i) tv[i] = vA[i];
        } else if (grow < N_NODES && k0 + 32 <= K) {
#pragma unroll
            for (int i = 0; i < 16; ++i)
                tv[i] = elu(vA[i] + bstage[k0 + af + i] + vN[i] * invd);
        } else {
#pragma unroll
            for (int i = 0; i < 16; ++i) {
                int k = k0 + af + i;
                float v = 0.0f;
                if (grow < N_NODES && k < K) v = elu(vA[i] + bstage[k] + vN[i] * invd);
                tv[i] = v;
            }
        }
        split_store16(&AsH[arow][af], &AsL[arow][af], tv);
        short8 hh8, ll8;
#pragma unroll
        for (int kk = 0; kk < 8; ++kk) {
            unsigned short hh, ll;
            split_bf16(vB[kk], hh, ll);
            hh8[kk] = (short)hh; ll8[kk] = (short)ll;
        }
        *(short8*)&BsH[bn][bkg * 8] = hh8;
        *(short8*)&BsL[bn][bkg * 8] = ll8;
    };

    float bufA[2][16], bufN[2][16], bufB[2][8];
    load_a(0, bufA[0], bufN[0]);
    load_b(0, bufB[0]);

#pragma unroll
    for (int t = 0; t < NSTEP; ++t) {
        const int cur = t & 1, nxt = cur ^ 1;
        if (t + 1 < NSTEP) {            // issue next tile's loads (fly under this step)
            load_a((t + 1) * 32, bufA[nxt], bufN[nxt]);
            load_b((t + 1) * 32, bufB[nxt]);
        }
        __syncthreads();                // prev-iter LDS readers done
        stage(t * 32, bufA[cur], bufN[cur], bufB[cur]);
        __syncthreads();                // LDS tile visible
        short8 ah[4], al[4];
#pragma unroll
        for (int fi = 0; fi < 4; ++fi) {
            ah[fi] = *(const short8*)&AsH[wm + fi * 16 + fr][fg * 8];
            al[fi] = *(const short8*)&AsL[wm + fi * 16 + fr][fg * 8];
        }
#pragma unroll
        for (int fj = 0; fj < 2; ++fj) {
            short8 bh = *(const short8*)&BsH[wn + fj * 16 + fr][fg * 8];
            short8 bl = *(const short8*)&BsL[wn + fj * 16 + fr][fg * 8];
#pragma unroll
            for (int fi = 0; fi < 4; ++fi) {
                acc[fi][fj] = __builtin_amdgcn_mfma_f32_16x16x32_bf16(ah[fi], bh, acc[fi][fj], 0, 0, 0);
                acc[fi][fj] = __builtin_amdgcn_mfma_f32_16x16x32_bf16(al[fi], bh, acc[fi][fj], 0, 0, 0);
                acc[fi][fj] = __builtin_amdgcn_mfma_f32_16x16x32_bf16(ah[fi], bl, acc[fi][fj], 0, 0, 0);
            }
        }
    }

    // ---- epilogue ----
#pragma unroll
    for (int fi = 0; fi < 4; ++fi) {
#pragma unroll
        for (int r = 0; r < 4; ++r) {
            int row = m0 + wm + fi * 16 + fg * 4 + r;
            if (row >= N_NODES) continue;
            float rmul = 1.0f;
            if (EPI == 1) rmul = rsqrtf(fmaxf((float)deg[row], 1.0f));
#pragma unroll
            for (int fj = 0; fj < 2; ++fj) {
                int col = n0 + wn + fj * 16 + fr;
                if (col >= LDC) continue;
                float v = 0.0f;
                if (col < NW) {
                    v = acc[fi][fj][r];
                    if (EPI == 1) v = elu(v * rmul + bepi[col]);
                    else if (EPI == 3) v = elu(v + bepi[col]);
                }
                C[(size_t)row * LDC + col] = v;
            }
        }
    }
}

// ---------------- gemm_dual (MFMA, pipelined): [p | h2pre] = h1 @ [Wn | Ws] ----------------
// 4 siblings (Wn-lo, Wn-hi, Ws-lo, Ws-hi) of each A row-panel land on the same XCD.
__global__ __launch_bounds__(256, 3)
void gemm_dual_mfma(const float* __restrict__ h1, const float* __restrict__ Wn,
                    const float* __restrict__ Ws, float* __restrict__ p,
                    float* __restrict__ h2pre) {
    constexpr int NSTEP = 5;   // KP=160
    constexpr int MBLK = (N_NODES + 127) / 128;
    __shared__ __align__(16) unsigned short AsH[128][LDS_K];
    __shared__ __align__(16) unsigned short AsL[128][LDS_K];
    __shared__ __align__(16) unsigned short BsH[64][LDS_K];
    __shared__ __align__(16) unsigned short BsL[64][LDS_K];

    const int b = blockIdx.x;
    const int c = b & 7;
    const int sIdx = b >> 3;
    const int jj = sIdx >> 2;           // GROUP=4
    const int yy = sIdx & 3;
    const int xb = c + 8 * jj;
    if (xb >= MBLK) return;
    const int m0 = xb * 128;
    const int n0 = (yy & 1) * 64;
    const float* W = (yy < 2) ? Wn : Ws;

    const int tid = threadIdx.x;
    const int arow = tid >> 1;
    const int af = (tid & 1) * 16;
    const int grow = m0 + arow;
    const int bn = tid & 63;
    const int bkg = tid >> 6;
    const int bcol = n0 + bn;
    const int wid = tid >> 6;
    const int lane = tid & 63;
    const int wm = (wid >> 1) * 64;
    const int wn = (wid & 1) * 32;
    const int fr = lane & 15;
    const int fg = lane >> 4;

    f32x4 acc[4][2];
#pragma unroll
    for (int i = 0; i < 4; ++i)
#pragma unroll
        for (int j = 0; j < 2; ++j) acc[i][j] = {0.0f, 0.0f, 0.0f, 0.0f};

    auto load_a = [&](int k0, float* vA) {
        if (grow < N_NODES && k0 + 32 <= D1) {
            const float* ap = h1 + (size_t)grow * LD1 + k0 + af;
#pragma unroll
            for (int h = 0; h < 4; ++h) {
                float4 v = *(const float4*)(ap + h * 4);
                vA[h * 4 + 0] = v.x; vA[h * 4 + 1] = v.y;
                vA[h * 4 + 2] = v.z; vA[h * 4 + 3] = v.w;
            }
        } else {
#pragma unroll
            for (int i = 0; i < 16; ++i) {
                int k = k0 + af + i;
                vA[i] = (grow < N_NODES && k < D1) ? h1[(size_t)grow * LD1 + k] : 0.0f;
            }
        }
    };
    auto load_b = [&](int k0, float* vB) {
#pragma unroll
        for (int kk = 0; kk < 8; ++kk) {
            int k = k0 + bkg * 8 + kk;
            vB[kk] = (k < D1 && bcol < D2) ? W[(size_t)k * D2 + bcol] : 0.0f;
        }
    };
    auto stage = [&](const float* vA, const float* vB) {
        split_store16(&AsH[arow][af], &AsL[arow][af], vA);
        short8 hh8, ll8;
#pragma unroll
        for (int kk = 0; kk < 8; ++kk) {
            unsigned short hh, ll;
            split_bf16(vB[kk], hh, ll);
            hh8[kk] = (short)hh; ll8[kk] = (short)ll;
        }
        *(short8*)&BsH[bn][bkg * 8] = hh8;
        *(short8*)&BsL[bn][bkg * 8] = ll8;
    };

    float bufA[2][16], bufB[2][8];
    load_a(0, bufA[0]);
    load_b(0, bufB[0]);

#pragma unroll
    for (int t = 0; t < NSTEP; ++t) {
        const int cur = t & 1, nxt = cur ^ 1;
        if (t + 1 < NSTEP) {
            load_a((t + 1) * 32, bufA[nxt]);
            load_b((t + 1) * 32, bufB[nxt]);
        }
        __syncthreads();
        stage(bufA[cur], bufB[cur]);
        __syncthreads();
        short8 ah[4], al[4];
#pragma unroll
        for (int fi = 0; fi < 4; ++fi) {
            ah[fi] = *(const short8*)&AsH[wm + fi * 16 + fr][fg * 8];
            al[fi] = *(const short8*)&AsL[wm + fi * 16 + fr][fg * 8];
        }
#pragma unroll
        for (int fj = 0; fj < 2; ++fj) {
            short8 bh = *(const short8*)&BsH[wn + fj * 16 + fr][fg * 8];
            short8 bl = *(const short8*)&BsL[wn + fj * 16 + fr][fg * 8];
#pragma unroll
            for (int fi = 0; fi < 4; ++fi) {
                acc[fi][fj] = __builtin_amdgcn_mfma_f32_16x16x32_bf16(ah[fi], bh, acc[fi][fj], 0, 0, 0);
                acc[fi][fj] = __builtin_amdgcn_mfma_f32_16x16x32_bf16(al[fi], bh, acc[fi][fj], 0, 0, 0);
                acc[fi][fj] = __builtin_amdgcn_mfma_f32_16x16x32_bf16(ah[fi], bl, acc[fi][fj], 0, 0, 0);
            }
        }
    }

#pragma unroll
    for (int fi = 0; fi < 4; ++fi) {
#pragma unroll
        for (int r = 0; r < 4; ++r) {
            int row = m0 + wm + fi * 16 + fg * 4 + r;
            if (row >= N_NODES) continue;
#pragma unroll
            for (int fj = 0; fj < 2; ++fj) {
                int col = n0 + wn + fj * 16 + fr;
                float v = acc[fi][fj][r];
                if (yy < 2) {
                    p[(size_t)row * LDP + col] = (col < D2) ? v : 0.0f;
                } else {
                    if (col < D2) h2pre[(size_t)row * D2 + col] = v;
                }
            }
        }
    }
}

extern "C" void kernel_launch(void* const* d_in, const int* in_sizes, int n_in,
                              void* d_out, int out_size, void* d_ws, size_t ws_size,
                              hipStream_t stream) {
    const float* x  = (const float*)d_in[0];
    const int* src  = (const int*)d_in[1];
    const int* dst  = (const int*)d_in[2];
    const float* W1 = (const float*)d_in[3];
    const float* b1 = (const float*)d_in[4];
    const float* Wn = (const float*)d_in[5];
    const float* Ws = (const float*)d_in[6];
    const float* b2 = (const float*)d_in[7];
    const float* W3 = (const float*)d_in[8];
    const float* b3 = (const float*)d_in[9];
    float* out = (float*)d_out;

    // workspace (4B elements), total 21.5M = 86 MB (layout proven R13):
    char* wsb = (char*)d_ws;
    unsigned int* partial = (unsigned int*)wsb;
    int*   cursor     = (int*)wsb + 800000;          // becomes deg_in
    float* norm_out   = (float*)wsb + 850000;
    unsigned short* slots = (unsigned short*)((float*)wsb + 900000);
    float* agg        = (float*)wsb + 2500000;
    float* h1         = (float*)wsb + 8900000;
    float* h2pre      = (float*)wsb + 16500000;
    float* p          = agg;   // overlay: agg dead after gemm1
    float* ns         = h1;    // overlay: h1 dead after gemm_dual
    int*   deg_in     = cursor;

    hipMemsetAsync(cursor, 0, N_NODES * sizeof(int), stream);

    hist_kernel<<<HBLK, 256, 0, stream>>>(src, partial);
    fill_kernel<<<(N_EDGES + 255) / 256, 256, 0, stream>>>(src, dst, cursor, slots);
    norm_kernel<<<(HBIN + 255) / 256, 256, 0, stream>>>(partial, norm_out);
    gather_x<<<(N_NODES + 3) / 4, 256, 0, stream>>>(x, norm_out, deg_in, slots, agg);

    const int MB = (N_NODES + 127) / 128;   // 391
    const int XG = (MB + 7) / 8;            // 49 x-panels per XCD slot-chunk
    // gemm1: h1 = elu(rsqrt(deg_in)*(agg @ W1) + b1)   [K=128, N=150, GROUP=3]
    gemm_mfma<128, 128, 150, 128, 0, 1, LD1, 3><<<XG * 8 * 3, 256, 0, stream>>>(
        agg, W1, nullptr, deg_in, nullptr, b1, h1);
    // dual: [p | h2pre] = h1 @ [Wn | Ws]  (GROUP=4 siblings per XCD)
    gemm_dual_mfma<<<XG * 8 * 4, 256, 0, stream>>>(h1, Wn, Ws, p, h2pre);
    gather_p<<<(N_NODES + 3) / 4, 256, 0, stream>>>(p, deg_in, slots, ns);
    // gemm3: out = elu( elu(h2pre + b2 + ns/deg) @ W3 + b3 )   [K=100, N=64, GROUP=1]
    gemm_mfma<100, 128, 64, 100, 1, 3, D_OUT, 1><<<XG * 8, 256, 0, stream>>>(
        h2pre, W3, ns, deg_in, b2, b3, out);
}

// Round 3
// 341.122 us; speedup vs baseline: 1.1020x; 1.1020x over previous
//
#include <hip/hip_runtime.h>
#include <math.h>

#define N_NODES 50000
#define N_EDGES 800000
#define D_IN 128
#define D1 150
#define LD1 152   // h1 leading dim (16B-aligned rows; pad cols written 0)
#define D2 100
#define LDP 128   // p / ns leading dim (alignment; pad cols written 0, never read)
#define D_OUT 64
#define SLOT 64   // fixed bucket capacity per dst node; P(deg_in>64) ~ 1e-15 (Poisson 16)
#define HBLK 64   // histogram shards (deg_out via LDS atomics)
#define HBIN 12500  // 50000 bins packed 4 x u8 per int

#define LDS_K 40  // LDS k-stride (32 used + 8 pad) -> 80B rows (16B-aligned), cyclic banks

using short8 = __attribute__((ext_vector_type(8))) short;   // 8 bf16 (4 VGPRs)
using f32x4  = __attribute__((ext_vector_type(4))) float;   // MFMA accumulator

__device__ __forceinline__ float elu(float v) { return v > 0.0f ? v : expm1f(v); }

// fp32 -> bf16 hi/lo split (round-to-nearest via +0x8000 trick).
__device__ __forceinline__ void split_bf16(float a, unsigned short& h, unsigned short& l) {
    unsigned int bits = __float_as_uint(a);
    unsigned int hb = (bits + 0x8000u) >> 16;
    h = (unsigned short)hb;
    float r = a - __uint_as_float(hb << 16);
    l = (unsigned short)((__float_as_uint(r) + 0x8000u) >> 16);
}

__device__ __forceinline__ void split8(const float4 a, const float4 b, short8& h, short8& l) {
    float f[8] = {a.x, a.y, a.z, a.w, b.x, b.y, b.z, b.w};
#pragma unroll
    for (int i = 0; i < 8; ++i) {
        unsigned short hh, ll;
        split_bf16(f[i], hh, ll);
        h[i] = (short)hh; l[i] = (short)ll;
    }
}

__device__ __forceinline__ float4 g_load4(const float* p) { return *(const float4*)p; }

__device__ __forceinline__ float4 g_load4_guard(const float* row, int kbase, int Klim, bool rowok) {
    float4 v;
    v.x = (rowok && kbase + 0 < Klim) ? row[kbase + 0] : 0.0f;
    v.y = (rowok && kbase + 1 < Klim) ? row[kbase + 1] : 0.0f;
    v.z = (rowok && kbase + 2 < Klim) ? row[kbase + 2] : 0.0f;
    v.w = (rowok && kbase + 3 < Klim) ? row[kbase + 3] : 0.0f;
    return v;
}

// lgkm-only barrier: LDS producer/consumer ordering WITHOUT draining vmcnt, so
// register-prefetch global loads stay in flight across it (unlike __syncthreads,
// which lowers to s_waitcnt vmcnt(0) lgkmcnt(0) + s_barrier).
__device__ __forceinline__ void barrier_lgkm() {
    asm volatile("s_waitcnt lgkmcnt(0)\n\ts_barrier" ::: "memory");
    __builtin_amdgcn_sched_barrier(0);
}

// ---------------- deg_out histogram via LDS atomics ----------------
__global__ __launch_bounds__(256) void hist_kernel(const int* __restrict__ src,
                                                   unsigned int* __restrict__ partial) {
    __shared__ unsigned int bins[HBIN];   // 50 KB
    int tid = threadIdx.x, b = blockIdx.x;
    for (int i = tid; i < HBIN; i += 256) bins[i] = 0u;
    __syncthreads();
    int e0 = b * (N_EDGES / HBLK);
    int e1 = e0 + (N_EDGES / HBLK);
    for (int e = e0 + tid; e < e1; e += 256) {
        int s = src[e];
        atomicAdd(&bins[s >> 2], 1u << ((s & 3) * 8));
    }
    __syncthreads();
    unsigned int* outp = partial + (size_t)b * HBIN;
    for (int i = tid; i < HBIN; i += 256) outp[i] = bins[i];
}

// ---------------- norm_out[n] = rsqrt(max(deg_out,1)) from packed partials ----------------
__global__ __launch_bounds__(256) void norm_kernel(const unsigned int* __restrict__ partial,
                                                   float* __restrict__ norm_out) {
    int i = blockIdx.x * blockDim.x + threadIdx.x;   // int position: 4 nodes
    if (i >= HBIN) return;
    unsigned int acc = 0;
#pragma unroll
    for (int h = 0; h < HBLK; ++h) acc += partial[(size_t)h * HBIN + i];
#pragma unroll
    for (int j = 0; j < 4; ++j) {
        unsigned int dg = (acc >> (j * 8)) & 0xFF;
        norm_out[i * 4 + j] = rsqrtf(fmaxf((float)dg, 1.0f));
    }
}

// ---------------- bucket fill: cursor atomic + slot store only (800k atomics) ----------------
__global__ void fill_kernel(const int* __restrict__ src, const int* __restrict__ dst,
                            int* __restrict__ cursor, unsigned short* __restrict__ slots) {
    int e = blockIdx.x * blockDim.x + threadIdx.x;
    if (e < N_EDGES) {
        int d = dst[e], s = src[e];
        int pos = atomicAdd(&cursor[d], 1);
        if (pos < SLOT) slots[d * SLOT + pos] = (unsigned short)s;
    }
}

// ---------------- gather 1: agg[n] = sum_e x[src[e]] * norm_out[src[e]] ----------------
__global__ __launch_bounds__(256) void gather_x(const float* __restrict__ x,
                                                const float* __restrict__ norm_out,
                                                const int* __restrict__ deg_in,
                                                const unsigned short* __restrict__ slots,
                                                float* __restrict__ agg) {
    int wave = threadIdx.x >> 6;
    int lane = threadIdx.x & 63;
    int half = lane >> 5;
    int c = lane & 31;
    int n = blockIdx.x * 4 + wave;
    if (n >= N_NODES) return;
    int beg = n * SLOT;
    int dg = deg_in[n]; if (dg > SLOT) dg = SLOT;
    int end = beg + dg;
    float4 acc = {0.0f, 0.0f, 0.0f, 0.0f};
    int e = beg + half;
    for (; e + 2 < end; e += 4) {
        int s0 = slots[e];
        int s1 = slots[e + 2];
        float w0 = norm_out[s0], w1 = norm_out[s1];
        float4 v0 = ((const float4*)(x + (size_t)s0 * D_IN))[c];
        float4 v1 = ((const float4*)(x + (size_t)s1 * D_IN))[c];
        acc.x += v0.x * w0 + v1.x * w1;
        acc.y += v0.y * w0 + v1.y * w1;
        acc.z += v0.z * w0 + v1.z * w1;
        acc.w += v0.w * w0 + v1.w * w1;
    }
    if (e < end) {
        int s = slots[e];
        float w = norm_out[s];
        float4 v = ((const float4*)(x + (size_t)s * D_IN))[c];
        acc.x += v.x * w; acc.y += v.y * w; acc.z += v.z * w; acc.w += v.w * w;
    }
    acc.x += __shfl_xor(acc.x, 32);
    acc.y += __shfl_xor(acc.y, 32);
    acc.z += __shfl_xor(acc.z, 32);
    acc.w += __shfl_xor(acc.w, 32);
    if (half == 0) ((float4*)(agg + (size_t)n * D_IN))[c] = acc;
}

// ---------------- gather 2: ns[n] = sum_e p[src[e]]  (only cols 0..99 read) ----------------
__global__ __launch_bounds__(256) void gather_p(const float* __restrict__ p,
                                                const int* __restrict__ deg_in,
                                                const unsigned short* __restrict__ slots,
                                                float* __restrict__ ns) {
    int wave = threadIdx.x >> 6;
    int lane = threadIdx.x & 63;
    int half = lane >> 5;
    int c = lane & 31;
    bool cv = c < D2 / 4;
    int n = blockIdx.x * 4 + wave;
    if (n >= N_NODES) return;
    int beg = n * SLOT;
    int dg = deg_in[n]; if (dg > SLOT) dg = SLOT;
    int end = beg + dg;
    float4 acc = {0.0f, 0.0f, 0.0f, 0.0f};
    if (cv) {
        int e = beg + half;
        for (; e + 2 < end; e += 4) {
            int s0 = slots[e];
            int s1 = slots[e + 2];
            float4 v0 = ((const float4*)(p + (size_t)s0 * LDP))[c];
            float4 v1 = ((const float4*)(p + (size_t)s1 * LDP))[c];
            acc.x += v0.x + v1.x;
            acc.y += v0.y + v1.y;
            acc.z += v0.z + v1.z;
            acc.w += v0.w + v1.w;
        }
        if (e < end) {
            int s = slots[e];
            float4 v = ((const float4*)(p + (size_t)s * LDP))[c];
            acc.x += v.x; acc.y += v.y; acc.z += v.z; acc.w += v.w;
        }
    }
    acc.x += __shfl_xor(acc.x, 32);
    acc.y += __shfl_xor(acc.y, 32);
    acc.z += __shfl_xor(acc.z, 32);
    acc.w += __shfl_xor(acc.w, 32);
    if (half == 0 && cv) ((float4*)(ns + (size_t)n * LDP))[c] = acc;
}

// ======================= split-bf16 MFMA GEMM, BM=64, reg-prefetch =======================
// BM=64, BN=64, BK=32. 4 waves 2Mx2N; wave tile 32x32 = 2x2 frags; 3 MFMAs/frag (hh,lh,hl).
// LDS 20.5 KB/block, __launch_bounds__(256,4) -> 4 blocks/CU (16 waves) for TLP.
// Prefetch: iter t issues tile t+1's global loads into named reg buffers (parity-indexed,
// unroll-folded -> stays in VGPRs); lgkm-only barriers keep those loads in flight across
// stage+MFMA of step t. XCD-sibling swizzle: GROUP n-siblings of an A row-panel land on
// consecutive slots of the SAME XCD -> panel L2-hit (proven R2: FETCH 90->16MB).
// C/D layout (verified): col = lane&15, row = (lane>>4)*4 + reg.

template <int K, int KP, int NW, int LDA, int PRE, int EPI, int LDC, int GROUP>
__global__ __launch_bounds__(256, 4)
void gemm_mfma(const float* __restrict__ A, const float* __restrict__ W,
               const float* __restrict__ nsrc, const int* __restrict__ deg,
               const float* __restrict__ bstage, const float* __restrict__ bepi,
               float* __restrict__ C) {
    constexpr int NSTEP = KP / 32;
    constexpr int MBLK = (N_NODES + 63) / 64;
    __shared__ __align__(16) unsigned short AsH[64][LDS_K];
    __shared__ __align__(16) unsigned short AsL[64][LDS_K];
    __shared__ __align__(16) unsigned short BsH[64][LDS_K];
    __shared__ __align__(16) unsigned short BsL[64][LDS_K];

    const int b = blockIdx.x;
    const int cxcd = b & 7;
    const int sIdx = b >> 3;
    const int jj = sIdx / GROUP;
    const int yy = sIdx - jj * GROUP;
    const int xb = cxcd + 8 * jj;
    if (xb >= MBLK) return;
    const int m0 = xb * 64;
    const int n0 = yy * 64;

    const int tid = threadIdx.x;
    // A staging: 4 threads/row, 8 contiguous k each (coalesced 128B/row)
    const int arow = tid >> 2;
    const int ak = (tid & 3) * 8;
    const int grow = m0 + arow;
    const bool rowok = grow < N_NODES;
    // B staging: thread = one column of W, 8 k values
    const int bn = tid & 63;
    const int bkg = tid >> 6;
    const int bcol = n0 + bn;
    // fragment coords
    const int wid = tid >> 6;
    const int lane = tid & 63;
    const int wm = (wid >> 1) * 32;
    const int wn = (wid & 1) * 32;
    const int fr = lane & 15;
    const int fg = lane >> 4;

    float invd = 1.0f;
    if (PRE) {
        int dv = rowok ? deg[grow] : 1;
        invd = 1.0f / fmaxf((float)dv, 1.0f);
    }

    f32x4 acc[2][2];
#pragma unroll
    for (int i = 0; i < 2; ++i)
#pragma unroll
        for (int j = 0; j < 2; ++j) acc[i][j] = {0.0f, 0.0f, 0.0f, 0.0f};

    const float* arp = A + (size_t)grow * LDA;
    const float* nrp = PRE ? (nsrc + (size_t)grow * LDP) : nullptr;

    float4 pa[2][2], pn[2][2];
    float pb[2][8];

    // prologue: tile 0 -> buffer 0
    {
        if (rowok && 32 <= K) {
            pa[0][0] = g_load4(arp + ak);
            pa[0][1] = g_load4(arp + ak + 4);
        } else {
            pa[0][0] = g_load4_guard(arp, ak, K, rowok);
            pa[0][1] = g_load4_guard(arp, ak + 4, K, rowok);
        }
        if (PRE) {
            if (rowok && 32 <= K) {
                pn[0][0] = g_load4(nrp + ak);
                pn[0][1] = g_load4(nrp + ak + 4);
            } else {
                pn[0][0] = g_load4_guard(nrp, ak, K, rowok);
                pn[0][1] = g_load4_guard(nrp, ak + 4, K, rowok);
            }
        }
#pragma unroll
        for (int kk = 0; kk < 8; ++kk) {
            int k = bkg * 8 + kk;
            pb[0][kk] = (k < K && bcol < NW) ? W[(size_t)k * NW + bcol] : 0.0f;
        }
    }

#pragma unroll
    for (int t = 0; t < NSTEP; ++t) {
        const int cur = t & 1, nxt = cur ^ 1;
        if (t + 1 < NSTEP) {   // issue next tile's loads; they fly across the lgkm barriers
            const int k0n = (t + 1) * 32;
            if (rowok && k0n + 32 <= K) {
                pa[nxt][0] = g_load4(arp + k0n + ak);
                pa[nxt][1] = g_load4(arp + k0n + ak + 4);
            } else {
                pa[nxt][0] = g_load4_guard(arp, k0n + ak, K, rowok);
                pa[nxt][1] = g_load4_guard(arp, k0n + ak + 4, K, rowok);
            }
            if (PRE) {
                if (rowok && k0n + 32 <= K) {
                    pn[nxt][0] = g_load4(nrp + k0n + ak);
                    pn[nxt][1] = g_load4(nrp + k0n + ak + 4);
                } else {
                    pn[nxt][0] = g_load4_guard(nrp, k0n + ak, K, rowok);
                    pn[nxt][1] = g_load4_guard(nrp, k0n + ak + 4, K, rowok);
                }
            }
#pragma unroll
            for (int kk = 0; kk < 8; ++kk) {
                int k = k0n + bkg * 8 + kk;
                pb[nxt][kk] = (k < K && bcol < NW) ? W[(size_t)k * NW + bcol] : 0.0f;
            }
        }
        barrier_lgkm();   // prev step's ds_reads done; safe to overwrite LDS
        {
            const int k0 = t * 32;
            float4 va0 = pa[cur][0], va1 = pa[cur][1];
            if (PRE) {
                const float4 vn0 = pn[cur][0], vn1 = pn[cur][1];
                if (k0 + 32 <= K) {
                    va0.x = elu(va0.x + bstage[k0 + ak + 0] + vn0.x * invd);
                    va0.y = elu(va0.y + bstage[k0 + ak + 1] + vn0.y * invd);
                    va0.z = elu(va0.z + bstage[k0 + ak + 2] + vn0.z * invd);
                    va0.w = elu(va0.w + bstage[k0 + ak + 3] + vn0.w * invd);
                    va1.x = elu(va1.x + bstage[k0 + ak + 4] + vn1.x * invd);
                    va1.y = elu(va1.y + bstage[k0 + ak + 5] + vn1.y * invd);
                    va1.z = elu(va1.z + bstage[k0 + ak + 6] + vn1.z * invd);
                    va1.w = elu(va1.w + bstage[k0 + ak + 7] + vn1.w * invd);
                } else {
                    va0.x = (k0 + ak + 0 < K) ? elu(va0.x + bstage[k0 + ak + 0] + vn0.x * invd) : 0.0f;
                    va0.y = (k0 + ak + 1 < K) ? elu(va0.y + bstage[k0 + ak + 1] + vn0.y * invd) : 0.0f;
                    va0.z = (k0 + ak + 2 < K) ? elu(va0.z + bstage[k0 + ak + 2] + vn0.z * invd) : 0.0f;
                    va0.w = (k0 + ak + 3 < K) ? elu(va0.w + bstage[k0 + ak + 3] + vn0.w * invd) : 0.0f;
                    va1.x = (k0 + ak + 4 < K) ? elu(va1.x + bstage[k0 + ak + 4] + vn1.x * invd) : 0.0f;
                    va1.y = (k0 + ak + 5 < K) ? elu(va1.y + bstage[k0 + ak + 5] + vn1.y * invd) : 0.0f;
                    va1.z = (k0 + ak + 6 < K) ? elu(va1.z + bstage[k0 + ak + 6] + vn1.z * invd) : 0.0f;
                    va1.w = (k0 + ak + 7 < K) ? elu(va1.w + bstage[k0 + ak + 7] + vn1.w * invd) : 0.0f;
                }
            }
            short8 h8, l8;
            split8(va0, va1, h8, l8);
            *(short8*)&AsH[arow][ak] = h8;
            *(short8*)&AsL[arow][ak] = l8;
            float4 vb0, vb1;
            vb0.x = pb[cur][0]; vb0.y = pb[cur][1]; vb0.z = pb[cur][2]; vb0.w = pb[cur][3];
            vb1.x = pb[cur][4]; vb1.y = pb[cur][5]; vb1.z = pb[cur][6]; vb1.w = pb[cur][7];
            split8(vb0, vb1, h8, l8);
            *(short8*)&BsH[bn][bkg * 8] = h8;
            *(short8*)&BsL[bn][bkg * 8] = l8;
        }
        barrier_lgkm();   // tile visible
        {
            short8 ah0 = *(const short8*)&AsH[wm + fr][fg * 8];
            short8 ah1 = *(const short8*)&AsH[wm + 16 + fr][fg * 8];
            short8 al0 = *(const short8*)&AsL[wm + fr][fg * 8];
            short8 al1 = *(const short8*)&AsL[wm + 16 + fr][fg * 8];
            short8 bh0 = *(const short8*)&BsH[wn + fr][fg * 8];
            short8 bh1 = *(const short8*)&BsH[wn + 16 + fr][fg * 8];
            short8 bl0 = *(const short8*)&BsL[wn + fr][fg * 8];
            short8 bl1 = *(const short8*)&BsL[wn + 16 + fr][fg * 8];
            acc[0][0] = __builtin_amdgcn_mfma_f32_16x16x32_bf16(ah0, bh0, acc[0][0], 0, 0, 0);
            acc[0][0] = __builtin_amdgcn_mfma_f32_16x16x32_bf16(al0, bh0, acc[0][0], 0, 0, 0);
            acc[0][0] = __builtin_amdgcn_mfma_f32_16x16x32_bf16(ah0, bl0, acc[0][0], 0, 0, 0);
            acc[0][1] = __builtin_amdgcn_mfma_f32_16x16x32_bf16(ah0, bh1, acc[0][1], 0, 0, 0);
            acc[0][1] = __builtin_amdgcn_mfma_f32_16x16x32_bf16(al0, bh1, acc[0][1], 0, 0, 0);
            acc[0][1] = __builtin_amdgcn_mfma_f32_16x16x32_bf16(ah0, bl1, acc[0][1], 0, 0, 0);
            acc[1][0] = __builtin_amdgcn_mfma_f32_16x16x32_bf16(ah1, bh0, acc[1][0], 0, 0, 0);
            acc[1][0] = __builtin_amdgcn_mfma_f32_16x16x32_bf16(al1, bh0, acc[1][0], 0, 0, 0);
            acc[1][0] = __builtin_amdgcn_mfma_f32_16x16x32_bf16(ah1, bl0, acc[1][0], 0, 0, 0);
            acc[1][1] = __builtin_amdgcn_mfma_f32_16x16x32_bf16(ah1, bh1, acc[1][1], 0, 0, 0);
            acc[1][1] = __builtin_amdgcn_mfma_f32_16x16x32_bf16(al1, bh1, acc[1][1], 0, 0, 0);
            acc[1][1] = __builtin_amdgcn_mfma_f32_16x16x32_bf16(ah1, bl1, acc[1][1], 0, 0, 0);
        }
    }

    // ---- epilogue ----
#pragma unroll
    for (int fi = 0; fi < 2; ++fi) {
#pragma unroll
        for (int r = 0; r < 4; ++r) {
            int row = m0 + wm + fi * 16 + fg * 4 + r;
            if (row >= N_NODES) continue;
            float rmul = 1.0f;
            if (EPI == 1) rmul = rsqrtf(fmaxf((float)deg[row], 1.0f));
#pragma unroll
            for (int fj = 0; fj < 2; ++fj) {
                int col = n0 + wn + fj * 16 + fr;
                if (col >= LDC) continue;
                float v = 0.0f;
                if (col < NW) {
                    v = acc[fi][fj][r];
                    if (EPI == 1) v = elu(v * rmul + bepi[col]);
                    else if (EPI == 3) v = elu(v + bepi[col]);
                }
                C[(size_t)row * LDC + col] = v;
            }
        }
    }
}

// ---------------- gemm_dual (MFMA, BM=64): [p | h2pre] = h1 @ [Wn | Ws] ----------------
// 4 siblings (Wn-lo, Wn-hi, Ws-lo, Ws-hi) of each A row-panel on the same XCD.
__global__ __launch_bounds__(256, 4)
void gemm_dual_mfma(const float* __restrict__ h1, const float* __restrict__ Wn,
                    const float* __restrict__ Ws, float* __restrict__ p,
                    float* __restrict__ h2pre) {
    constexpr int NSTEP = 5;   // KP=160, K=150
    constexpr int MBLK = (N_NODES + 63) / 64;
    __shared__ __align__(16) unsigned short AsH[64][LDS_K];
    __shared__ __align__(16) unsigned short AsL[64][LDS_K];
    __shared__ __align__(16) unsigned short BsH[64][LDS_K];
    __shared__ __align__(16) unsigned short BsL[64][LDS_K];

    const int b = blockIdx.x;
    const int cxcd = b & 7;
    const int sIdx = b >> 3;
    const int jj = sIdx >> 2;           // GROUP=4
    const int yy = sIdx & 3;
    const int xb = cxcd + 8 * jj;
    if (xb >= MBLK) return;
    const int m0 = xb * 64;
    const int n0 = (yy & 1) * 64;
    const float* W = (yy < 2) ? Wn : Ws;

    const int tid = threadIdx.x;
    const int arow = tid >> 2;
    const int ak = (tid & 3) * 8;
    const int grow = m0 + arow;
    const bool rowok = grow < N_NODES;
    const int bn = tid & 63;
    const int bkg = tid >> 6;
    const int bcol = n0 + bn;
    const int wid = tid >> 6;
    const int lane = tid & 63;
    const int wm = (wid >> 1) * 32;
    const int wn = (wid & 1) * 32;
    const int fr = lane & 15;
    const int fg = lane >> 4;

    f32x4 acc[2][2];
#pragma unroll
    for (int i = 0; i < 2; ++i)
#pragma unroll
        for (int j = 0; j < 2; ++j) acc[i][j] = {0.0f, 0.0f, 0.0f, 0.0f};

    const float* arp = h1 + (size_t)grow * LD1;

    float4 pa[2][2];
    float pb[2][8];

    {
        if (rowok) {
            pa[0][0] = g_load4(arp + ak);
            pa[0][1] = g_load4(arp + ak + 4);
        } else {
            pa[0][0] = g_load4_guard(arp, ak, D1, rowok);
            pa[0][1] = g_load4_guard(arp, ak + 4, D1, rowok);
        }
#pragma unroll
        for (int kk = 0; kk < 8; ++kk) {
            int k = bkg * 8 + kk;
            pb[0][kk] = (k < D1 && bcol < D2) ? W[(size_t)k * D2 + bcol] : 0.0f;
        }
    }

#pragma unroll
    for (int t = 0; t < NSTEP; ++t) {
        const int cur = t & 1, nxt = cur ^ 1;
        if (t + 1 < NSTEP) {
            const int k0n = (t + 1) * 32;
            if (rowok && k0n + 32 <= D1) {
                pa[nxt][0] = g_load4(arp + k0n + ak);
                pa[nxt][1] = g_load4(arp + k0n + ak + 4);
            } else {
                pa[nxt][0] = g_load4_guard(arp, k0n + ak, D1, rowok);
                pa[nxt][1] = g_load4_guard(arp, k0n + ak + 4, D1, rowok);
            }
#pragma unroll
            for (int kk = 0; kk < 8; ++kk) {
                int k = k0n + bkg * 8 + kk;
                pb[nxt][kk] = (k < D1 && bcol < D2) ? W[(size_t)k * D2 + bcol] : 0.0f;
            }
        }
        barrier_lgkm();
        {
            short8 h8, l8;
            split8(pa[cur][0], pa[cur][1], h8, l8);
            *(short8*)&AsH[arow][ak] = h8;
            *(short8*)&AsL[arow][ak] = l8;
            float4 vb0, vb1;
            vb0.x = pb[cur][0]; vb0.y = pb[cur][1]; vb0.z = pb[cur][2]; vb0.w = pb[cur][3];
            vb1.x = pb[cur][4]; vb1.y = pb[cur][5]; vb1.z = pb[cur][6]; vb1.w = pb[cur][7];
            split8(vb0, vb1, h8, l8);
            *(short8*)&BsH[bn][bkg * 8] = h8;
            *(short8*)&BsL[bn][bkg * 8] = l8;
        }
        barrier_lgkm();
        {
            short8 ah0 = *(const short8*)&AsH[wm + fr][fg * 8];
            short8 ah1 = *(const short8*)&AsH[wm + 16 + fr][fg * 8];
            short8 al0 = *(const short8*)&AsL[wm + fr][fg * 8];
            short8 al1 = *(const short8*)&AsL[wm + 16 + fr][fg * 8];
            short8 bh0 = *(const short8*)&BsH[wn + fr][fg * 8];
            short8 bh1 = *(const short8*)&BsH[wn + 16 + fr][fg * 8];
            short8 bl0 = *(const short8*)&BsL[wn + fr][fg * 8];
            short8 bl1 = *(const short8*)&BsL[wn + 16 + fr][fg * 8];
            acc[0][0] = __builtin_amdgcn_mfma_f32_16x16x32_bf16(ah0, bh0, acc[0][0], 0, 0, 0);
            acc[0][0] = __builtin_amdgcn_mfma_f32_16x16x32_bf16(al0, bh0, acc[0][0], 0, 0, 0);
            acc[0][0] = __builtin_amdgcn_mfma_f32_16x16x32_bf16(ah0, bl0, acc[0][0], 0, 0, 0);
            acc[0][1] = __builtin_amdgcn_mfma_f32_16x16x32_bf16(ah0, bh1, acc[0][1], 0, 0, 0);
            acc[0][1] = __builtin_amdgcn_mfma_f32_16x16x32_bf16(al0, bh1, acc[0][1], 0, 0, 0);
            acc[0][1] = __builtin_amdgcn_mfma_f32_16x16x32_bf16(ah0, bl1, acc[0][1], 0, 0, 0);
            acc[1][0] = __builtin_amdgcn_mfma_f32_16x16x32_bf16(ah1, bh0, acc[1][0], 0, 0, 0);
            acc[1][0] = __builtin_amdgcn_mfma_f32_16x16x32_bf16(al1, bh0, acc[1][0], 0, 0, 0);
            acc[1][0] = __builtin_amdgcn_mfma_f32_16x16x32_bf16(ah1, bl0, acc[1][0], 0, 0, 0);
            acc[1][1] = __builtin_amdgcn_mfma_f32_16x16x32_bf16(ah1, bh1, acc[1][1], 0, 0, 0);
            acc[1][1] = __builtin_amdgcn_mfma_f32_16x16x32_bf16(al1, bh1, acc[1][1], 0, 0, 0);
            acc[1][1] = __builtin_amdgcn_mfma_f32_16x16x32_bf16(ah1, bl1, acc[1][1], 0, 0, 0);
        }
    }

#pragma unroll
    for (int fi = 0; fi < 2; ++fi) {
#pragma unroll
        for (int r = 0; r < 4; ++r) {
            int row = m0 + wm + fi * 16 + fg * 4 + r;
            if (row >= N_NODES) continue;
#pragma unroll
            for (int fj = 0; fj < 2; ++fj) {
                int col = n0 + wn + fj * 16 + fr;
                float v = acc[fi][fj][r];
                if (yy < 2) {
                    p[(size_t)row * LDP + col] = (col < D2) ? v : 0.0f;
                } else {
                    if (col < D2) h2pre[(size_t)row * D2 + col] = v;
                }
            }
        }
    }
}

extern "C" void kernel_launch(void* const* d_in, const int* in_sizes, int n_in,
                              void* d_out, int out_size, void* d_ws, size_t ws_size,
                              hipStream_t stream) {
    const float* x  = (const float*)d_in[0];
    const int* src  = (const int*)d_in[1];
    const int* dst  = (const int*)d_in[2];
    const float* W1 = (const float*)d_in[3];
    const float* b1 = (const float*)d_in[4];
    const float* Wn = (const float*)d_in[5];
    const float* Ws = (const float*)d_in[6];
    const float* b2 = (const float*)d_in[7];
    const float* W3 = (const float*)d_in[8];
    const float* b3 = (const float*)d_in[9];
    float* out = (float*)d_out;

    // workspace (4B elements), total 21.5M = 86 MB (layout proven R13):
    char* wsb = (char*)d_ws;
    unsigned int* partial = (unsigned int*)wsb;
    int*   cursor     = (int*)wsb + 800000;          // becomes deg_in
    float* norm_out   = (float*)wsb + 850000;
    unsigned short* slots = (unsigned short*)((float*)wsb + 900000);
    float* agg        = (float*)wsb + 2500000;
    float* h1         = (float*)wsb + 8900000;
    float* h2pre      = (float*)wsb + 16500000;
    float* p          = agg;   // overlay: agg dead after gemm1
    float* ns         = h1;    // overlay: h1 dead after gemm_dual
    int*   deg_in     = cursor;

    hipMemsetAsync(cursor, 0, N_NODES * sizeof(int), stream);

    hist_kernel<<<HBLK, 256, 0, stream>>>(src, partial);
    fill_kernel<<<(N_EDGES + 255) / 256, 256, 0, stream>>>(src, dst, cursor, slots);
    norm_kernel<<<(HBIN + 255) / 256, 256, 0, stream>>>(partial, norm_out);
    gather_x<<<(N_NODES + 3) / 4, 256, 0, stream>>>(x, norm_out, deg_in, slots, agg);

    const int MB = (N_NODES + 63) / 64;     // 782 row-panels
    const int XG = (MB + 7) / 8;            // 98 panels per XCD slot-chunk
    // gemm1: h1 = elu(rsqrt(deg_in)*(agg @ W1) + b1)   [K=128, N=150, GROUP=3]
    gemm_mfma<128, 128, 150, 128, 0, 1, LD1, 3><<<XG * 8 * 3, 256, 0, stream>>>(
        agg, W1, nullptr, deg_in, nullptr, b1, h1);
    // dual: [p | h2pre] = h1 @ [Wn | Ws]  (GROUP=4 siblings per XCD)
    gemm_dual_mfma<<<XG * 8 * 4, 256, 0, stream>>>(h1, Wn, Ws, p, h2pre);
    gather_p<<<(N_NODES + 3) / 4, 256, 0, stream>>>(p, deg_in, slots, ns);
    // gemm3: out = elu( elu(h2pre + b2 + ns/deg) @ W3 + b3 )   [K=100, N=64, GROUP=1]
    gemm_mfma<100, 128, 64, 100, 1, 3, D_OUT, 1><<<XG * 8, 256, 0, stream>>>(
        h2pre, W3, ns, deg_in, b2, b3, out);
}

// Round 4
// 330.436 us; speedup vs baseline: 1.1377x; 1.0323x over previous
//
#include <hip/hip_runtime.h>
#include <math.h>

#define N_NODES 50000
#define N_EDGES 800000
#define D_IN 128
#define D1 150
#define LD1 152   // h1 leading dim (16B-aligned rows; pad cols written 0)
#define D2 100
#define LDP 100   // p / ns leading dim: PACKED (400B rows, 16B-aligned) — no pad fetched
#define D_OUT 64
#define SLOT 64   // fixed bucket capacity per dst node; P(deg_in>64) ~ 1e-15 (Poisson 16)
#define HBLK 64   // histogram shards (deg_out via LDS atomics)
#define HBIN 12500  // 50000 bins packed 4 x u8 per int

#define LDS_K 40  // LDS k-stride (32 used + 8 pad) -> 80B rows (16B-aligned), cyclic banks

using short8 = __attribute__((ext_vector_type(8))) short;   // 8 bf16 (4 VGPRs)
using f32x4  = __attribute__((ext_vector_type(4))) float;   // MFMA accumulator

__device__ __forceinline__ float elu(float v) { return v > 0.0f ? v : expm1f(v); }

// fp32 -> bf16 hi/lo split (round-to-nearest via +0x8000 trick).
__device__ __forceinline__ void split_bf16(float a, unsigned short& h, unsigned short& l) {
    unsigned int bits = __float_as_uint(a);
    unsigned int hb = (bits + 0x8000u) >> 16;
    h = (unsigned short)hb;
    float r = a - __uint_as_float(hb << 16);
    l = (unsigned short)((__float_as_uint(r) + 0x8000u) >> 16);
}

__device__ __forceinline__ void split8(const float4 a, const float4 b, short8& h, short8& l) {
    float f[8] = {a.x, a.y, a.z, a.w, b.x, b.y, b.z, b.w};
#pragma unroll
    for (int i = 0; i < 8; ++i) {
        unsigned short hh, ll;
        split_bf16(f[i], hh, ll);
        h[i] = (short)hh; l[i] = (short)ll;
    }
}

__device__ __forceinline__ float4 g_load4(const float* p) { return *(const float4*)p; }

__device__ __forceinline__ float4 g_load4_guard(const float* row, int kbase, int Klim, bool rowok) {
    float4 v;
    v.x = (rowok && kbase + 0 < Klim) ? row[kbase + 0] : 0.0f;
    v.y = (rowok && kbase + 1 < Klim) ? row[kbase + 1] : 0.0f;
    v.z = (rowok && kbase + 2 < Klim) ? row[kbase + 2] : 0.0f;
    v.w = (rowok && kbase + 3 < Klim) ? row[kbase + 3] : 0.0f;
    return v;
}

// lgkm-only barrier: LDS producer/consumer ordering WITHOUT draining vmcnt, so
// register-prefetch global loads stay in flight across it (unlike __syncthreads,
// which lowers to s_waitcnt vmcnt(0) lgkmcnt(0) + s_barrier).
__device__ __forceinline__ void barrier_lgkm() {
    asm volatile("s_waitcnt lgkmcnt(0)\n\ts_barrier" ::: "memory");
    __builtin_amdgcn_sched_barrier(0);
}

// ---------------- deg_out histogram via LDS atomics ----------------
__global__ __launch_bounds__(256) void hist_kernel(const int* __restrict__ src,
                                                   unsigned int* __restrict__ partial) {
    __shared__ unsigned int bins[HBIN];   // 50 KB
    int tid = threadIdx.x, b = blockIdx.x;
    for (int i = tid; i < HBIN; i += 256) bins[i] = 0u;
    __syncthreads();
    int e0 = b * (N_EDGES / HBLK);
    int e1 = e0 + (N_EDGES / HBLK);
    for (int e = e0 + tid; e < e1; e += 256) {
        int s = src[e];
        atomicAdd(&bins[s >> 2], 1u << ((s & 3) * 8));
    }
    __syncthreads();
    unsigned int* outp = partial + (size_t)b * HBIN;
    for (int i = tid; i < HBIN; i += 256) outp[i] = bins[i];
}

// ---------------- norm_out[n] = rsqrt(max(deg_out,1)) from packed partials ----------------
__global__ __launch_bounds__(256) void norm_kernel(const unsigned int* __restrict__ partial,
                                                   float* __restrict__ norm_out) {
    int i = blockIdx.x * blockDim.x + threadIdx.x;   // int position: 4 nodes
    if (i >= HBIN) return;
    unsigned int acc = 0;
#pragma unroll
    for (int h = 0; h < HBLK; ++h) acc += partial[(size_t)h * HBIN + i];
#pragma unroll
    for (int j = 0; j < 4; ++j) {
        unsigned int dg = (acc >> (j * 8)) & 0xFF;
        norm_out[i * 4 + j] = rsqrtf(fmaxf((float)dg, 1.0f));
    }
}

// ---------------- bucket fill: cursor atomic + slot store only (800k atomics) ----------------
__global__ void fill_kernel(const int* __restrict__ src, const int* __restrict__ dst,
                            int* __restrict__ cursor, unsigned short* __restrict__ slots) {
    int e = blockIdx.x * blockDim.x + threadIdx.x;
    if (e < N_EDGES) {
        int d = dst[e], s = src[e];
        int pos = atomicAdd(&cursor[d], 1);
        if (pos < SLOT) slots[d * SLOT + pos] = (unsigned short)s;
    }
}

// ---------------- gather 1: agg[n] = sum_e x[src[e]] * norm_out[src[e]] ----------------
// unroll-4 per half-wave: 8 row-streams in flight per node (MLP for the random-read path)
__global__ __launch_bounds__(256) void gather_x(const float* __restrict__ x,
                                                const float* __restrict__ norm_out,
                                                const int* __restrict__ deg_in,
                                                const unsigned short* __restrict__ slots,
                                                float* __restrict__ agg) {
    int wave = threadIdx.x >> 6;
    int lane = threadIdx.x & 63;
    int half = lane >> 5;
    int c = lane & 31;
    int n = blockIdx.x * 4 + wave;
    if (n >= N_NODES) return;
    int beg = n * SLOT;
    int dg = deg_in[n]; if (dg > SLOT) dg = SLOT;
    int end = beg + dg;
    float4 acc = {0.0f, 0.0f, 0.0f, 0.0f};
    int e = beg + half;
    for (; e + 6 < end; e += 8) {
        int s0 = slots[e];
        int s1 = slots[e + 2];
        int s2 = slots[e + 4];
        int s3 = slots[e + 6];
        float w0 = norm_out[s0], w1 = norm_out[s1];
        float w2 = norm_out[s2], w3 = norm_out[s3];
        float4 v0 = ((const float4*)(x + (size_t)s0 * D_IN))[c];
        float4 v1 = ((const float4*)(x + (size_t)s1 * D_IN))[c];
        float4 v2 = ((const float4*)(x + (size_t)s2 * D_IN))[c];
        float4 v3 = ((const float4*)(x + (size_t)s3 * D_IN))[c];
        acc.x += v0.x * w0 + v1.x * w1 + v2.x * w2 + v3.x * w3;
        acc.y += v0.y * w0 + v1.y * w1 + v2.y * w2 + v3.y * w3;
        acc.z += v0.z * w0 + v1.z * w1 + v2.z * w2 + v3.z * w3;
        acc.w += v0.w * w0 + v1.w * w1 + v2.w * w2 + v3.w * w3;
    }
    for (; e < end; e += 2) {
        int s = slots[e];
        float w = norm_out[s];
        float4 v = ((const float4*)(x + (size_t)s * D_IN))[c];
        acc.x += v.x * w; acc.y += v.y * w; acc.z += v.z * w; acc.w += v.w * w;
    }
    acc.x += __shfl_xor(acc.x, 32);
    acc.y += __shfl_xor(acc.y, 32);
    acc.z += __shfl_xor(acc.z, 32);
    acc.w += __shfl_xor(acc.w, 32);
    if (half == 0) ((float4*)(agg + (size_t)n * D_IN))[c] = acc;
}

// ---------------- gather 2: ns[n] = sum_e p[src[e]]  (packed LDP=100, 400B rows) ----------------
__global__ __launch_bounds__(256) void gather_p(const float* __restrict__ p,
                                                const int* __restrict__ deg_in,
                                                const unsigned short* __restrict__ slots,
                                                float* __restrict__ ns) {
    int wave = threadIdx.x >> 6;
    int lane = threadIdx.x & 63;
    int half = lane >> 5;
    int c = lane & 31;
    bool cv = c < D2 / 4;   // 25 active float4 lanes cover 100 cols
    int n = blockIdx.x * 4 + wave;
    if (n >= N_NODES) return;
    int beg = n * SLOT;
    int dg = deg_in[n]; if (dg > SLOT) dg = SLOT;
    int end = beg + dg;
    float4 acc = {0.0f, 0.0f, 0.0f, 0.0f};
    if (cv) {
        int e = beg + half;
        for (; e + 6 < end; e += 8) {
            int s0 = slots[e];
            int s1 = slots[e + 2];
            int s2 = slots[e + 4];
            int s3 = slots[e + 6];
            float4 v0 = ((const float4*)(p + (size_t)s0 * LDP))[c];
            float4 v1 = ((const float4*)(p + (size_t)s1 * LDP))[c];
            float4 v2 = ((const float4*)(p + (size_t)s2 * LDP))[c];
            float4 v3 = ((const float4*)(p + (size_t)s3 * LDP))[c];
            acc.x += (v0.x + v1.x) + (v2.x + v3.x);
            acc.y += (v0.y + v1.y) + (v2.y + v3.y);
            acc.z += (v0.z + v1.z) + (v2.z + v3.z);
            acc.w += (v0.w + v1.w) + (v2.w + v3.w);
        }
        for (; e < end; e += 2) {
            int s = slots[e];
            float4 v = ((const float4*)(p + (size_t)s * LDP))[c];
            acc.x += v.x; acc.y += v.y; acc.z += v.z; acc.w += v.w;
        }
    }
    acc.x += __shfl_xor(acc.x, 32);
    acc.y += __shfl_xor(acc.y, 32);
    acc.z += __shfl_xor(acc.z, 32);
    acc.w += __shfl_xor(acc.w, 32);
    if (half == 0 && cv) ((float4*)(ns + (size_t)n * LDP))[c] = acc;
}

// ======================= split-bf16 MFMA GEMM, BM=64, reg-prefetch =======================
// BM=64, BN=64, BK=32. 4 waves 2Mx2N; wave tile 32x32 = 2x2 frags; 3 MFMAs/frag (hh,lh,hl).
// LDS 20.5 KB/block, __launch_bounds__(256,4) -> 4 blocks/CU (16 waves) for TLP.
// Prefetch: iter t issues tile t+1's global loads into named reg buffers (parity-indexed,
// unroll-folded -> stays in VGPRs); lgkm-only barriers keep those loads in flight across
// stage+MFMA of step t. XCD-sibling swizzle: GROUP n-siblings of an A row-panel land on
// consecutive slots of the SAME XCD -> panel L2-hit (proven R2: FETCH 90->16MB).
// C/D layout (verified): col = lane&15, row = (lane>>4)*4 + reg.

template <int K, int KP, int NW, int LDA, int PRE, int EPI, int LDC, int GROUP>
__global__ __launch_bounds__(256, 4)
void gemm_mfma(const float* __restrict__ A, const float* __restrict__ W,
               const float* __restrict__ nsrc, const int* __restrict__ deg,
               const float* __restrict__ bstage, const float* __restrict__ bepi,
               float* __restrict__ C) {
    constexpr int NSTEP = KP / 32;
    constexpr int MBLK = (N_NODES + 63) / 64;
    __shared__ __align__(16) unsigned short AsH[64][LDS_K];
    __shared__ __align__(16) unsigned short AsL[64][LDS_K];
    __shared__ __align__(16) unsigned short BsH[64][LDS_K];
    __shared__ __align__(16) unsigned short BsL[64][LDS_K];

    const int b = blockIdx.x;
    const int cxcd = b & 7;
    const int sIdx = b >> 3;
    const int jj = sIdx / GROUP;
    const int yy = sIdx - jj * GROUP;
    const int xb = cxcd + 8 * jj;
    if (xb >= MBLK) return;
    const int m0 = xb * 64;
    const int n0 = yy * 64;

    const int tid = threadIdx.x;
    // A staging: 4 threads/row, 8 contiguous k each (coalesced 128B/row)
    const int arow = tid >> 2;
    const int ak = (tid & 3) * 8;
    const int grow = m0 + arow;
    const bool rowok = grow < N_NODES;
    // B staging: thread = one column of W, 8 k values
    const int bn = tid & 63;
    const int bkg = tid >> 6;
    const int bcol = n0 + bn;
    // fragment coords
    const int wid = tid >> 6;
    const int lane = tid & 63;
    const int wm = (wid >> 1) * 32;
    const int wn = (wid & 1) * 32;
    const int fr = lane & 15;
    const int fg = lane >> 4;

    float invd = 1.0f;
    if (PRE) {
        int dv = rowok ? deg[grow] : 1;
        invd = 1.0f / fmaxf((float)dv, 1.0f);
    }

    f32x4 acc[2][2];
#pragma unroll
    for (int i = 0; i < 2; ++i)
#pragma unroll
        for (int j = 0; j < 2; ++j) acc[i][j] = {0.0f, 0.0f, 0.0f, 0.0f};

    const float* arp = A + (size_t)grow * LDA;
    const float* nrp = PRE ? (nsrc + (size_t)grow * LDP) : nullptr;

    float4 pa[2][2], pn[2][2];
    float pb[2][8];

    // prologue: tile 0 -> buffer 0
    {
        if (rowok && 32 <= K) {
            pa[0][0] = g_load4(arp + ak);
            pa[0][1] = g_load4(arp + ak + 4);
        } else {
            pa[0][0] = g_load4_guard(arp, ak, K, rowok);
            pa[0][1] = g_load4_guard(arp, ak + 4, K, rowok);
        }
        if (PRE) {
            if (rowok && 32 <= K) {
                pn[0][0] = g_load4(nrp + ak);
                pn[0][1] = g_load4(nrp + ak + 4);
            } else {
                pn[0][0] = g_load4_guard(nrp, ak, K, rowok);
                pn[0][1] = g_load4_guard(nrp, ak + 4, K, rowok);
            }
        }
#pragma unroll
        for (int kk = 0; kk < 8; ++kk) {
            int k = bkg * 8 + kk;
            pb[0][kk] = (k < K && bcol < NW) ? W[(size_t)k * NW + bcol] : 0.0f;
        }
    }

#pragma unroll
    for (int t = 0; t < NSTEP; ++t) {
        const int cur = t & 1, nxt = cur ^ 1;
        if (t + 1 < NSTEP) {   // issue next tile's loads; they fly across the lgkm barriers
            const int k0n = (t + 1) * 32;
            if (rowok && k0n + 32 <= K) {
                pa[nxt][0] = g_load4(arp + k0n + ak);
                pa[nxt][1] = g_load4(arp + k0n + ak + 4);
            } else {
                pa[nxt][0] = g_load4_guard(arp, k0n + ak, K, rowok);
                pa[nxt][1] = g_load4_guard(arp, k0n + ak + 4, K, rowok);
            }
            if (PRE) {
                if (rowok && k0n + 32 <= K) {
                    pn[nxt][0] = g_load4(nrp + k0n + ak);
                    pn[nxt][1] = g_load4(nrp + k0n + ak + 4);
                } else {
                    pn[nxt][0] = g_load4_guard(nrp, k0n + ak, K, rowok);
                    pn[nxt][1] = g_load4_guard(nrp, k0n + ak + 4, K, rowok);
                }
            }
#pragma unroll
            for (int kk = 0; kk < 8; ++kk) {
                int k = k0n + bkg * 8 + kk;
                pb[nxt][kk] = (k < K && bcol < NW) ? W[(size_t)k * NW + bcol] : 0.0f;
            }
        }
        barrier_lgkm();   // prev step's ds_reads done; safe to overwrite LDS
        {
            const int k0 = t * 32;
            float4 va0 = pa[cur][0], va1 = pa[cur][1];
            if (PRE) {
                const float4 vn0 = pn[cur][0], vn1 = pn[cur][1];
                if (k0 + 32 <= K) {
                    va0.x = elu(va0.x + bstage[k0 + ak + 0] + vn0.x * invd);
                    va0.y = elu(va0.y + bstage[k0 + ak + 1] + vn0.y * invd);
                    va0.z = elu(va0.z + bstage[k0 + ak + 2] + vn0.z * invd);
                    va0.w = elu(va0.w + bstage[k0 + ak + 3] + vn0.w * invd);
                    va1.x = elu(va1.x + bstage[k0 + ak + 4] + vn1.x * invd);
                    va1.y = elu(va1.y + bstage[k0 + ak + 5] + vn1.y * invd);
                    va1.z = elu(va1.z + bstage[k0 + ak + 6] + vn1.z * invd);
                    va1.w = elu(va1.w + bstage[k0 + ak + 7] + vn1.w * invd);
                } else {
                    va0.x = (k0 + ak + 0 < K) ? elu(va0.x + bstage[k0 + ak + 0] + vn0.x * invd) : 0.0f;
                    va0.y = (k0 + ak + 1 < K) ? elu(va0.y + bstage[k0 + ak + 1] + vn0.y * invd) : 0.0f;
                    va0.z = (k0 + ak + 2 < K) ? elu(va0.z + bstage[k0 + ak + 2] + vn0.z * invd) : 0.0f;
                    va0.w = (k0 + ak + 3 < K) ? elu(va0.w + bstage[k0 + ak + 3] + vn0.w * invd) : 0.0f;
                    va1.x = (k0 + ak + 4 < K) ? elu(va1.x + bstage[k0 + ak + 4] + vn1.x * invd) : 0.0f;
                    va1.y = (k0 + ak + 5 < K) ? elu(va1.y + bstage[k0 + ak + 5] + vn1.y * invd) : 0.0f;
                    va1.z = (k0 + ak + 6 < K) ? elu(va1.z + bstage[k0 + ak + 6] + vn1.z * invd) : 0.0f;
                    va1.w = (k0 + ak + 7 < K) ? elu(va1.w + bstage[k0 + ak + 7] + vn1.w * invd) : 0.0f;
                }
            }
            short8 h8, l8;
            split8(va0, va1, h8, l8);
            *(short8*)&AsH[arow][ak] = h8;
            *(short8*)&AsL[arow][ak] = l8;
            float4 vb0, vb1;
            vb0.x = pb[cur][0]; vb0.y = pb[cur][1]; vb0.z = pb[cur][2]; vb0.w = pb[cur][3];
            vb1.x = pb[cur][4]; vb1.y = pb[cur][5]; vb1.z = pb[cur][6]; vb1.w = pb[cur][7];
            split8(vb0, vb1, h8, l8);
            *(short8*)&BsH[bn][bkg * 8] = h8;
            *(short8*)&BsL[bn][bkg * 8] = l8;
        }
        barrier_lgkm();   // tile visible
        {
            short8 ah0 = *(const short8*)&AsH[wm + fr][fg * 8];
            short8 ah1 = *(const short8*)&AsH[wm + 16 + fr][fg * 8];
            short8 al0 = *(const short8*)&AsL[wm + fr][fg * 8];
            short8 al1 = *(const short8*)&AsL[wm + 16 + fr][fg * 8];
            short8 bh0 = *(const short8*)&BsH[wn + fr][fg * 8];
            short8 bh1 = *(const short8*)&BsH[wn + 16 + fr][fg * 8];
            short8 bl0 = *(const short8*)&BsL[wn + fr][fg * 8];
            short8 bl1 = *(const short8*)&BsL[wn + 16 + fr][fg * 8];
            acc[0][0] = __builtin_amdgcn_mfma_f32_16x16x32_bf16(ah0, bh0, acc[0][0], 0, 0, 0);
            acc[0][0] = __builtin_amdgcn_mfma_f32_16x16x32_bf16(al0, bh0, acc[0][0], 0, 0, 0);
            acc[0][0] = __builtin_amdgcn_mfma_f32_16x16x32_bf16(ah0, bl0, acc[0][0], 0, 0, 0);
            acc[0][1] = __builtin_amdgcn_mfma_f32_16x16x32_bf16(ah0, bh1, acc[0][1], 0, 0, 0);
            acc[0][1] = __builtin_amdgcn_mfma_f32_16x16x32_bf16(al0, bh1, acc[0][1], 0, 0, 0);
            acc[0][1] = __builtin_amdgcn_mfma_f32_16x16x32_bf16(ah0, bl1, acc[0][1], 0, 0, 0);
            acc[1][0] = __builtin_amdgcn_mfma_f32_16x16x32_bf16(ah1, bh0, acc[1][0], 0, 0, 0);
            acc[1][0] = __builtin_amdgcn_mfma_f32_16x16x32_bf16(al1, bh0, acc[1][0], 0, 0, 0);
            acc[1][0] = __builtin_amdgcn_mfma_f32_16x16x32_bf16(ah1, bl0, acc[1][0], 0, 0, 0);
            acc[1][1] = __builtin_amdgcn_mfma_f32_16x16x32_bf16(ah1, bh1, acc[1][1], 0, 0, 0);
            acc[1][1] = __builtin_amdgcn_mfma_f32_16x16x32_bf16(al1, bh1, acc[1][1], 0, 0, 0);
            acc[1][1] = __builtin_amdgcn_mfma_f32_16x16x32_bf16(ah1, bl1, acc[1][1], 0, 0, 0);
        }
    }

    // ---- epilogue ----
#pragma unroll
    for (int fi = 0; fi < 2; ++fi) {
#pragma unroll
        for (int r = 0; r < 4; ++r) {
            int row = m0 + wm + fi * 16 + fg * 4 + r;
            if (row >= N_NODES) continue;
            float rmul = 1.0f;
            if (EPI == 1) rmul = rsqrtf(fmaxf((float)deg[row], 1.0f));
#pragma unroll
            for (int fj = 0; fj < 2; ++fj) {
                int col = n0 + wn + fj * 16 + fr;
                if (col >= LDC) continue;
                float v = 0.0f;
                if (col < NW) {
                    v = acc[fi][fj][r];
                    if (EPI == 1) v = elu(v * rmul + bepi[col]);
                    else if (EPI == 3) v = elu(v + bepi[col]);
                }
                C[(size_t)row * LDC + col] = v;
            }
        }
    }
}

// ---------------- gemm_dual (MFMA, BM=64): [p | h2pre] = h1 @ [Wn | Ws] ----------------
// 4 siblings (Wn-lo, Wn-hi, Ws-lo, Ws-hi) of each A row-panel on the same XCD.
__global__ __launch_bounds__(256, 4)
void gemm_dual_mfma(const float* __restrict__ h1, const float* __restrict__ Wn,
                    const float* __restrict__ Ws, float* __restrict__ p,
                    float* __restrict__ h2pre) {
    constexpr int NSTEP = 5;   // KP=160, K=150
    constexpr int MBLK = (N_NODES + 63) / 64;
    __shared__ __align__(16) unsigned short AsH[64][LDS_K];
    __shared__ __align__(16) unsigned short AsL[64][LDS_K];
    __shared__ __align__(16) unsigned short BsH[64][LDS_K];
    __shared__ __align__(16) unsigned short BsL[64][LDS_K];

    const int b = blockIdx.x;
    const int cxcd = b & 7;
    const int sIdx = b >> 3;
    const int jj = sIdx >> 2;           // GROUP=4
    const int yy = sIdx & 3;
    const int xb = cxcd + 8 * jj;
    if (xb >= MBLK) return;
    const int m0 = xb * 64;
    const int n0 = (yy & 1) * 64;
    const float* W = (yy < 2) ? Wn : Ws;

    const int tid = threadIdx.x;
    const int arow = tid >> 2;
    const int ak = (tid & 3) * 8;
    const int grow = m0 + arow;
    const bool rowok = grow < N_NODES;
    const int bn = tid & 63;
    const int bkg = tid >> 6;
    const int bcol = n0 + bn;
    const int wid = tid >> 6;
    const int lane = tid & 63;
    const int wm = (wid >> 1) * 32;
    const int wn = (wid & 1) * 32;
    const int fr = lane & 15;
    const int fg = lane >> 4;

    f32x4 acc[2][2];
#pragma unroll
    for (int i = 0; i < 2; ++i)
#pragma unroll
        for (int j = 0; j < 2; ++j) acc[i][j] = {0.0f, 0.0f, 0.0f, 0.0f};

    const float* arp = h1 + (size_t)grow * LD1;

    float4 pa[2][2];
    float pb[2][8];

    {
        if (rowok) {
            pa[0][0] = g_load4(arp + ak);
            pa[0][1] = g_load4(arp + ak + 4);
        } else {
            pa[0][0] = g_load4_guard(arp, ak, D1, rowok);
            pa[0][1] = g_load4_guard(arp, ak + 4, D1, rowok);
        }
#pragma unroll
        for (int kk = 0; kk < 8; ++kk) {
            int k = bkg * 8 + kk;
            pb[0][kk] = (k < D1 && bcol < D2) ? W[(size_t)k * D2 + bcol] : 0.0f;
        }
    }

#pragma unroll
    for (int t = 0; t < NSTEP; ++t) {
        const int cur = t & 1, nxt = cur ^ 1;
        if (t + 1 < NSTEP) {
            const int k0n = (t + 1) * 32;
            if (rowok && k0n + 32 <= D1) {
                pa[nxt][0] = g_load4(arp + k0n + ak);
                pa[nxt][1] = g_load4(arp + k0n + ak + 4);
            } else {
                pa[nxt][0] = g_load4_guard(arp, k0n + ak, D1, rowok);
                pa[nxt][1] = g_load4_guard(arp, k0n + ak + 4, D1, rowok);
            }
#pragma unroll
            for (int kk = 0; kk < 8; ++kk) {
                int k = k0n + bkg * 8 + kk;
                pb[nxt][kk] = (k < D1 && bcol < D2) ? W[(size_t)k * D2 + bcol] : 0.0f;
            }
        }
        barrier_lgkm();
        {
            short8 h8, l8;
            split8(pa[cur][0], pa[cur][1], h8, l8);
            *(short8*)&AsH[arow][ak] = h8;
            *(short8*)&AsL[arow][ak] = l8;
            float4 vb0, vb1;
            vb0.x = pb[cur][0]; vb0.y = pb[cur][1]; vb0.z = pb[cur][2]; vb0.w = pb[cur][3];
            vb1.x = pb[cur][4]; vb1.y = pb[cur][5]; vb1.z = pb[cur][6]; vb1.w = pb[cur][7];
            split8(vb0, vb1, h8, l8);
            *(short8*)&BsH[bn][bkg * 8] = h8;
            *(short8*)&BsL[bn][bkg * 8] = l8;
        }
        barrier_lgkm();
        {
            short8 ah0 = *(const short8*)&AsH[wm + fr][fg * 8];
            short8 ah1 = *(const short8*)&AsH[wm + 16 + fr][fg * 8];
            short8 al0 = *(const short8*)&AsL[wm + fr][fg * 8];
            short8 al1 = *(const short8*)&AsL[wm + 16 + fr][fg * 8];
            short8 bh0 = *(const short8*)&BsH[wn + fr][fg * 8];
            short8 bh1 = *(const short8*)&BsH[wn + 16 + fr][fg * 8];
            short8 bl0 = *(const short8*)&BsL[wn + fr][fg * 8];
            short8 bl1 = *(const short8*)&BsL[wn + 16 + fr][fg * 8];
            acc[0][0] = __builtin_amdgcn_mfma_f32_16x16x32_bf16(ah0, bh0, acc[0][0], 0, 0, 0);
            acc[0][0] = __builtin_amdgcn_mfma_f32_16x16x32_bf16(al0, bh0, acc[0][0], 0, 0, 0);
            acc[0][0] = __builtin_amdgcn_mfma_f32_16x16x32_bf16(ah0, bl0, acc[0][0], 0, 0, 0);
            acc[0][1] = __builtin_amdgcn_mfma_f32_16x16x32_bf16(ah0, bh1, acc[0][1], 0, 0, 0);
            acc[0][1] = __builtin_amdgcn_mfma_f32_16x16x32_bf16(al0, bh1, acc[0][1], 0, 0, 0);
            acc[0][1] = __builtin_amdgcn_mfma_f32_16x16x32_bf16(ah0, bl1, acc[0][1], 0, 0, 0);
            acc[1][0] = __builtin_amdgcn_mfma_f32_16x16x32_bf16(ah1, bh0, acc[1][0], 0, 0, 0);
            acc[1][0] = __builtin_amdgcn_mfma_f32_16x16x32_bf16(al1, bh0, acc[1][0], 0, 0, 0);
            acc[1][0] = __builtin_amdgcn_mfma_f32_16x16x32_bf16(ah1, bl0, acc[1][0], 0, 0, 0);
            acc[1][1] = __builtin_amdgcn_mfma_f32_16x16x32_bf16(ah1, bh1, acc[1][1], 0, 0, 0);
            acc[1][1] = __builtin_amdgcn_mfma_f32_16x16x32_bf16(al1, bh1, acc[1][1], 0, 0, 0);
            acc[1][1] = __builtin_amdgcn_mfma_f32_16x16x32_bf16(ah1, bl1, acc[1][1], 0, 0, 0);
        }
    }

#pragma unroll
    for (int fi = 0; fi < 2; ++fi) {
#pragma unroll
        for (int r = 0; r < 4; ++r) {
            int row = m0 + wm + fi * 16 + fg * 4 + r;
            if (row >= N_NODES) continue;
#pragma unroll
            for (int fj = 0; fj < 2; ++fj) {
                int col = n0 + wn + fj * 16 + fr;
                float v = acc[fi][fj][r];
                if (col < D2) {
                    // packed LDP=100 rows: NEVER write col>=100 (would hit the next row)
                    if (yy < 2) p[(size_t)row * LDP + col] = v;
                    else        h2pre[(size_t)row * D2 + col] = v;
                }
            }
        }
    }
}

extern "C" void kernel_launch(void* const* d_in, const int* in_sizes, int n_in,
                              void* d_out, int out_size, void* d_ws, size_t ws_size,
                              hipStream_t stream) {
    const float* x  = (const float*)d_in[0];
    const int* src  = (const int*)d_in[1];
    const int* dst  = (const int*)d_in[2];
    const float* W1 = (const float*)d_in[3];
    const float* b1 = (const float*)d_in[4];
    const float* Wn = (const float*)d_in[5];
    const float* Ws = (const float*)d_in[6];
    const float* b2 = (const float*)d_in[7];
    const float* W3 = (const float*)d_in[8];
    const float* b3 = (const float*)d_in[9];
    float* out = (float*)d_out;

    // workspace (4B elements), total 21.5M = 86 MB (layout proven R13):
    char* wsb = (char*)d_ws;
    unsigned int* partial = (unsigned int*)wsb;
    int*   cursor     = (int*)wsb + 800000;          // becomes deg_in
    float* norm_out   = (float*)wsb + 850000;
    unsigned short* slots = (unsigned short*)((float*)wsb + 900000);
    float* agg        = (float*)wsb + 2500000;
    float* h1         = (float*)wsb + 8900000;
    float* h2pre      = (float*)wsb + 16500000;
    float* p          = agg;   // overlay: agg dead after gemm1 (p: 50000x100 packed = 20MB < 25.6MB)
    float* ns         = h1;    // overlay: h1 dead after gemm_dual (ns: 20MB < h1 region)
    int*   deg_in     = cursor;

    hipMemsetAsync(cursor, 0, N_NODES * sizeof(int), stream);

    hist_kernel<<<HBLK, 256, 0, stream>>>(src, partial);
    fill_kernel<<<(N_EDGES + 255) / 256, 256, 0, stream>>>(src, dst, cursor, slots);
    norm_kernel<<<(HBIN + 255) / 256, 256, 0, stream>>>(partial, norm_out);
    gather_x<<<(N_NODES + 3) / 4, 256, 0, stream>>>(x, norm_out, deg_in, slots, agg);

    const int MB = (N_NODES + 63) / 64;     // 782 row-panels
    const int XG = (MB + 7) / 8;            // 98 panels per XCD slot-chunk
    // gemm1: h1 = elu(rsqrt(deg_in)*(agg @ W1) + b1)   [K=128, N=150, GROUP=3]
    gemm_mfma<128, 128, 150, 128, 0, 1, LD1, 3><<<XG * 8 * 3, 256, 0, stream>>>(
        agg, W1, nullptr, deg_in, nullptr, b1, h1);
    // dual: [p | h2pre] = h1 @ [Wn | Ws]  (GROUP=4 siblings per XCD)
    gemm_dual_mfma<<<XG * 8 * 4, 256, 0, stream>>>(h1, Wn, Ws, p, h2pre);
    gather_p<<<(N_NODES + 3) / 4, 256, 0, stream>>>(p, deg_in, slots, ns);
    // gemm3: out = elu( elu(h2pre + b2 + ns/deg) @ W3 + b3 )   [K=100, N=64, GROUP=1]
    gemm_mfma<100, 128, 64, 100, 1, 3, D_OUT, 1><<<XG * 8, 256, 0, stream>>>(
        h2pre, W3, ns, deg_in, b2, b3, out);
}